// Round 1
// baseline (410.841 us; speedup 1.0000x reference)
//
#include <hip/hip_runtime.h>
#include <hip/hip_bf16.h>

// DecoderLayer cross-attention, MI355X/gfx950. Round 4.
// B=4, Sq=2048, Skv=4096, D=512. fp32 in/out, bf16 MFMA internally.
// R4 changes vs R3:
//  - attn: BM 64->32 (oacc 128->64 regs), __launch_bounds__(256,3) -> 3 blocks/CU
//          (occupancy 2->3 waves/SIMD; was double-capped by regs 252 and LDS 78KB).
//  - attn: s_setprio(1) around MFMA clusters (T5, phase-diverse blocks).
//  - cvt: 5 launches merged into 1 (launch-overhead trim).
// ws layout (phase-overlapped), unchanged:
//   Qb  bf16 [8192][512]      @ 0           (8,388,608)
//   Kb  bf16 [16384][512]     @ 8,388,608   (16,777,216)
//   Vt  bf16 [4][512][4096]   @ 25,165,824  (16,777,216)
//   region B @ 41,943,040:
//     phase1 (pre-proj): xb 8.4M | encb @+8.4M 16.8M | wqb/wkb/wvb @+25.2M 0.5M each
//     phase2 (attn):     Op f32 [NSPLIT][8192][512] | lp f32 [NSPLIT][8192]
//   need(NSPLIT=4) = 109,182,976 B ; need(NSPLIT=2) = 75,563,008 B (known available)

typedef __bf16 bf16;
typedef __attribute__((ext_vector_type(8))) __bf16 bf16x8;
typedef __attribute__((ext_vector_type(4))) float f32x4;

#define DM 512

// ---------------- fp32 -> bf16 convert prepass (single launch, 5 regions) -----------------
// region sizes in n8 units: x 524288 | enc 1048576 | wq 32768 | wk 32768 | wv 32768
// total 1,671,168 n8 -> grid 6528 x 256.
__global__ __launch_bounds__(256) void cvt_all_kernel(
    const float* __restrict__ x,   bf16* __restrict__ xb,
    const float* __restrict__ enc, bf16* __restrict__ encb,
    const float* __restrict__ wq,  bf16* __restrict__ wqb,
    const float* __restrict__ wk,  bf16* __restrict__ wkb,
    const float* __restrict__ wv,  bf16* __restrict__ wvb)
{
    int g = blockIdx.x * 256 + threadIdx.x;
    const float* src; bf16* dst;
    if (g < 524288)       { src = x;   dst = xb; }
    else if (g < 1572864) { g -= 524288;  src = enc; dst = encb; }
    else if (g < 1605632) { g -= 1572864; src = wq;  dst = wqb; }
    else if (g < 1638400) { g -= 1605632; src = wk;  dst = wkb; }
    else                  { g -= 1638400; src = wv;  dst = wvb; }
    const float4 f0 = *reinterpret_cast<const float4*>(src + (size_t)g * 8);
    const float4 f1 = *reinterpret_cast<const float4*>(src + (size_t)g * 8 + 4);
    bf16x8 v;
    v[0]=(bf16)f0.x; v[1]=(bf16)f0.y; v[2]=(bf16)f0.z; v[3]=(bf16)f0.w;
    v[4]=(bf16)f1.x; v[5]=(bf16)f1.y; v[6]=(bf16)f1.z; v[7]=(bf16)f1.w;
    *reinterpret_cast<bf16x8*>(dst + (size_t)g * 8) = v;
}

// ---------------- Projection GEMMs (bf16 in): out = A @ W^T + b, stored bf16 ---------------
// KV=false: Q row-major. KV=true: K row-major + V transposed Vt[b][e][t].
template<bool KV>
__global__ __launch_bounds__(256) void proj_kernel(const bf16* __restrict__ A,
    const bf16* __restrict__ W0, const float* __restrict__ b0, bf16* __restrict__ out0,
    const bf16* __restrict__ W1, const float* __restrict__ b1, bf16* __restrict__ out1)
{
    __shared__ __align__(16) bf16 As[2][64][40];
    __shared__ __align__(16) bf16 W0s[2][64][40];
    __shared__ __align__(16) bf16 W1s[2][64][40];

    const int tid  = threadIdx.x;
    const int w    = tid >> 6, lane = tid & 63, quad = lane >> 4, l15 = lane & 15;
    const int wr   = w >> 1, wc = w & 1;
    const int n0   = blockIdx.x * 64;
    const int m0   = blockIdx.y * 64;
    const int srow = tid >> 2;
    const int scol = (tid & 3) * 8;

    f32x4 acc0[2][2] = {}, acc1[2][2] = {};
    bf16x8 ra, rw0, rw1;

    auto prefetch = [&](int kk) {
        ra  = *reinterpret_cast<const bf16x8*>(A  + (size_t)(m0 + srow) * DM + kk + scol);
        rw0 = *reinterpret_cast<const bf16x8*>(W0 + (size_t)(n0 + srow) * DM + kk + scol);
        if constexpr (KV)
            rw1 = *reinterpret_cast<const bf16x8*>(W1 + (size_t)(n0 + srow) * DM + kk + scol);
    };
    auto store_lds = [&](int p) {
        *reinterpret_cast<bf16x8*>(&As[p][srow][scol])  = ra;
        *reinterpret_cast<bf16x8*>(&W0s[p][srow][scol]) = rw0;
        if constexpr (KV)
            *reinterpret_cast<bf16x8*>(&W1s[p][srow][scol]) = rw1;
    };

    prefetch(0);
    store_lds(0);
    __syncthreads();

    for (int step = 0; step < 16; step++) {
        const int p = step & 1;
        if (step < 15) prefetch((step + 1) * 32);

        bf16x8 af[2], bf0[2], bf1[2];
#pragma unroll
        for (int mt = 0; mt < 2; mt++)
            af[mt] = *reinterpret_cast<const bf16x8*>(&As[p][32*wr + 16*mt + l15][quad*8]);
#pragma unroll
        for (int nt = 0; nt < 2; nt++)
            bf0[nt] = *reinterpret_cast<const bf16x8*>(&W0s[p][32*wc + 16*nt + l15][quad*8]);
        if constexpr (KV) {
#pragma unroll
            for (int nt = 0; nt < 2; nt++)
                bf1[nt] = *reinterpret_cast<const bf16x8*>(&W1s[p][32*wc + 16*nt + l15][quad*8]);
        }
#pragma unroll
        for (int mt = 0; mt < 2; mt++)
#pragma unroll
            for (int nt = 0; nt < 2; nt++) {
                acc0[mt][nt] = __builtin_amdgcn_mfma_f32_16x16x32_bf16(af[mt], bf0[nt], acc0[mt][nt], 0, 0, 0);
                if constexpr (KV)
                    acc1[mt][nt] = __builtin_amdgcn_mfma_f32_16x16x32_bf16(af[mt], bf1[nt], acc1[mt][nt], 0, 0, 0);
            }

        if (step < 15) store_lds(p ^ 1);
        __syncthreads();
    }

#pragma unroll
    for (int mt = 0; mt < 2; mt++)
#pragma unroll
        for (int nt = 0; nt < 2; nt++) {
            const int coll = 32*wc + 16*nt + l15;
            const int rowl = 32*wr + 16*mt + quad*4;
            {
                const float bv = b0[n0 + coll];
                f32x4 c = acc0[mt][nt];
#pragma unroll
                for (int r = 0; r < 4; r++)
                    out0[(size_t)(m0 + rowl + r) * DM + n0 + coll] = (bf16)(c[r] + bv);
            }
            if constexpr (KV) {
                const float bv = b1[n0 + coll];
                f32x4 c = acc1[mt][nt];
                const int gr = m0 + rowl;
                const int bidx = gr >> 12, t = gr & 4095;
                const int e = n0 + coll;
                union { uint2 u; bf16 h[4]; } pk;
#pragma unroll
                for (int r = 0; r < 4; r++) pk.h[r] = (bf16)(c[r] + bv);
                *reinterpret_cast<uint2*>(out1 + (((size_t)(bidx * 512 + e)) << 12) + t) = pk.u;
            }
        }
}

// ---------------- Fused attention: BM=32, BN=64, no-max online softmax ---------------------
// 4 waves. QK: wave w owns kv cols [16w,16w+16), all 32 q rows (A from LDS Qs, B from global).
// PV: wave w owns D cols [128w,128w+128) (A = P from LDS, B = V from global, full-line reads).
// 2 barriers/tile (P transpose). oacc 2x8 f32x4 (64 regs) -> target 3 blocks/CU.
template<int NSPLIT>
__global__ __launch_bounds__(256, 3) void attn_kernel(const bf16* __restrict__ Qb,
                                                      const bf16* __restrict__ Kb,
                                                      const bf16* __restrict__ Vt,
                                                      float* __restrict__ Op,
                                                      float* __restrict__ lp)
{
    __shared__ __align__(16) bf16 Qs[32][520];   // 33,280 B; 260 dw stride -> uniform banks
    __shared__ __align__(16) bf16 Ps[32][80];    //  5,120 B; 40 dw stride -> uniform banks
    __shared__ float lred[32];

    const int tid  = threadIdx.x;
    const int w    = tid >> 6, lane = tid & 63, quad = lane >> 4, l15 = lane & 15;

    // XCD-swizzle: group all q-blocks of one (b,z) combo on one XCD (L2 locality).
    const int id = blockIdx.x;                   // 1D grid, 256*NSPLIT blocks
    const int xcd = id & 7, slot = id >> 3;
    int combo, qblk;
    if (NSPLIT == 4) { combo = xcd * 2 + (slot >> 6); qblk = slot & 63; }
    else             { combo = xcd;                   qblk = slot;      }
    const int b = combo & 3, z = combo >> 2;
    const int q0 = qblk * 32;
    const int KVLEN = 4096 / NSPLIT, NT = KVLEN / 64, tb = z * KVLEN;

    // stage Q tile [32][512] once
    {
        const bf16* src = Qb + (size_t)(b * 2048 + q0) * DM;
#pragma unroll
        for (int i = 0; i < 8; i++) {
            const int G = tid + 256 * i;         // 2048 chunks of 16 B
            const int row = G >> 6, cg = G & 63;
            *reinterpret_cast<bf16x8*>(&Qs[row][cg * 8]) =
                *reinterpret_cast<const bf16x8*>(src + (size_t)row * DM + cg * 8);
        }
    }
    if (tid < 32) lred[tid] = 0.f;
    __syncthreads();

    f32x4 oacc[2][8] = {};
    float lsum[2][4] = {};
    const float kexp = 1.44269504088896f * 0.044194173824159216f;  // log2(e)/sqrt(512)

    const bf16* krow0 = Kb + (size_t)(b * 4096 + tb + 16*w + l15) * DM + quad * 8;
    const bf16* vrow0 = Vt + ((size_t)(b * 512 + 128*w + l15) << 12) + tb + quad * 8;

    for (int tt = 0; tt < NT; tt++) {
        f32x4 sacc[2] = {};
        const bf16* krow = krow0 + (size_t)tt * 64 * DM;
#pragma unroll 4
        for (int k4 = 0; k4 < 16; k4++) {
            bf16x8 bfr = *reinterpret_cast<const bf16x8*>(krow + k4 * 32);
            __builtin_amdgcn_s_setprio(1);
#pragma unroll
            for (int mt = 0; mt < 2; mt++) {
                bf16x8 afr = *reinterpret_cast<const bf16x8*>(&Qs[16*mt + l15][k4*32 + quad*8]);
                sacc[mt] = __builtin_amdgcn_mfma_f32_16x16x32_bf16(afr, bfr, sacc[mt], 0, 0, 0);
            }
            __builtin_amdgcn_s_setprio(0);
        }

        // exp, accumulate l, P -> LDS (C-layout -> A-layout)
#pragma unroll
        for (int mt = 0; mt < 2; mt++)
#pragma unroll
            for (int r = 0; r < 4; r++) {
                const float p = exp2f(sacc[mt][r] * kexp);
                lsum[mt][r] += p;
                Ps[16*mt + quad*4 + r][16*w + l15] = (bf16)p;
            }
        __syncthreads();

        // PV: O[32, 128w..] += P[32,64] * V[64, 128w..]
        const bf16* vrow = vrow0 + tt * 64;
#pragma unroll
        for (int ks2 = 0; ks2 < 2; ks2++) {
            bf16x8 ap[2];
#pragma unroll
            for (int mt = 0; mt < 2; mt++)
                ap[mt] = *reinterpret_cast<const bf16x8*>(&Ps[16*mt + l15][ks2*32 + quad*8]);
#pragma unroll
            for (int nt = 0; nt < 8; nt++) {
                bf16x8 vf = *reinterpret_cast<const bf16x8*>(vrow + ((size_t)(16*nt) << 12) + ks2*32);
                __builtin_amdgcn_s_setprio(1);
#pragma unroll
                for (int mt = 0; mt < 2; mt++)
                    oacc[mt][nt] = __builtin_amdgcn_mfma_f32_16x16x32_bf16(ap[mt], vf, oacc[mt][nt], 0, 0, 0);
                __builtin_amdgcn_s_setprio(0);
            }
        }
        __syncthreads();   // protect Ps for next tile
    }

    // l reduction across lanes/waves
#pragma unroll
    for (int mt = 0; mt < 2; mt++)
#pragma unroll
        for (int r = 0; r < 4; r++)
            atomicAdd(&lred[16*mt + quad*4 + r], lsum[mt][r]);
    __syncthreads();

    if (tid < 32) lp[(size_t)z * 8192 + b * 2048 + q0 + tid] = lred[tid];
#pragma unroll
    for (int mt = 0; mt < 2; mt++)
#pragma unroll
        for (int r = 0; r < 4; r++) {
            const int row = 16*mt + quad*4 + r;
            float* obase = Op + ((size_t)z * 8192 + b * 2048 + q0 + row) * DM;
#pragma unroll
            for (int nt = 0; nt < 8; nt++)
                obase[128*w + 16*nt + l15] = oacc[mt][nt][r];
        }
}

// ---------------- Combine split partials: out = sum_z Op[z] / sum_z l[z] -------------------
template<int NSPLIT>
__global__ __launch_bounds__(256) void reduce_kernel(const float* __restrict__ Op,
                                                     const float* __restrict__ lp,
                                                     float* __restrict__ out)
{
    const int g = blockIdx.x * 256 + threadIdx.x;    // 1,048,576 threads x float4
    const size_t e = (size_t)g * 4;
    const int row = g >> 7;
    float4 o = *reinterpret_cast<const float4*>(Op + e);
    float l = lp[row];
#pragma unroll
    for (int zz = 1; zz < NSPLIT; zz++) {
        float4 a = *reinterpret_cast<const float4*>(Op + (size_t)zz * 4194304 + e);
        o.x += a.x; o.y += a.y; o.z += a.z; o.w += a.w;
        l += lp[zz * 8192 + row];
    }
    const float linv = 1.0f / l;
    o.x *= linv; o.y *= linv; o.z *= linv; o.w *= linv;
    *reinterpret_cast<float4*>(out + e) = o;
}

extern "C" void kernel_launch(void* const* d_in, const int* in_sizes, int n_in,
                              void* d_out, int out_size, void* d_ws, size_t ws_size,
                              hipStream_t stream)
{
    const float* x   = (const float*)d_in[0];
    const float* enc = (const float*)d_in[1];
    const float* wq  = (const float*)d_in[2];
    const float* bq  = (const float*)d_in[3];
    const float* wk  = (const float*)d_in[4];
    const float* bk  = (const float*)d_in[5];
    const float* wv  = (const float*)d_in[6];
    const float* bv  = (const float*)d_in[7];
    float* out = (float*)d_out;

    char* ws = (char*)d_ws;
    bf16*  Qb   = (bf16*)ws;
    bf16*  Kb   = (bf16*)(ws + 8388608);
    bf16*  Vt   = (bf16*)(ws + 25165824);
    bf16*  xb   = (bf16*)(ws + 41943040);
    bf16*  encb = (bf16*)(ws + 50331648);
    bf16*  wqb  = (bf16*)(ws + 67108864);
    bf16*  wkb  = (bf16*)(ws + 67633152);
    bf16*  wvb  = (bf16*)(ws + 68157440);
    float* Op   = (float*)(ws + 41943040);          // overlaps xb/encb/w*b (phase 2)
    // lp placed after Op per NSPLIT below

    // prepass: fp32 -> bf16, single launch
    hipLaunchKernelGGL(cvt_all_kernel, dim3(6528), dim3(256), 0, stream,
                       x, xb, enc, encb, wq, wqb, wk, wkb, wv, wvb);

    // projections
    hipLaunchKernelGGL((proj_kernel<false>), dim3(8, 128), dim3(256), 0, stream,
                       xb, wqb, bq, Qb, (const bf16*)nullptr, (const float*)nullptr, (bf16*)nullptr);
    hipLaunchKernelGGL((proj_kernel<true>),  dim3(8, 256), dim3(256), 0, stream,
                       encb, wkb, bk, Kb, wvb, bv, Vt);

    // attention + combine
    if (ws_size >= 109182976ull) {
        float* lp = (float*)(ws + 41943040 + 4ull * 16777216);
        hipLaunchKernelGGL((attn_kernel<4>), dim3(1024), dim3(256), 0, stream, Qb, Kb, Vt, Op, lp);
        hipLaunchKernelGGL((reduce_kernel<4>), dim3(4096), dim3(256), 0, stream, Op, lp, out);
    } else {
        float* lp = (float*)(ws + 41943040 + 2ull * 16777216);
        hipLaunchKernelGGL((attn_kernel<2>), dim3(512), dim3(256), 0, stream, Qb, Kb, Vt, Op, lp);
        hipLaunchKernelGGL((reduce_kernel<2>), dim3(4096), dim3(256), 0, stream, Op, lp, out);
    }
}